// Round 1
// baseline (165.271 us; speedup 1.0000x reference)
//
#include <hip/hip_runtime.h>
#include <hip/hip_bf16.h>

#define SEQ   2048
#define DM    1024
#define NH    16
#define DH    64
#define MAXD  128

#define LOG2E 1.44269504f

typedef __attribute__((ext_vector_type(8))) short  short8;   // 8 bf16 = 4 VGPRs
typedef __attribute__((ext_vector_type(4))) float  float4v;  // MFMA 16x16 accumulator

__device__ __forceinline__ short8 ld8(const void* p) {
    short8 v; __builtin_memcpy(&v, p, 16); return v;
}
__device__ __forceinline__ void st8(void* p, short8 v) {
    __builtin_memcpy(p, &v, 16);
}
__device__ __forceinline__ short bf16bits(float f) {
    __hip_bfloat16 b = __float2bfloat16(f);
    short s; __builtin_memcpy(&s, &b, 2); return s;
}
// fast bf16 pack: round-half-up (2 VALU ops). Used on P in [0,1].
__device__ __forceinline__ short bf16fast(float f) {
    unsigned u = __builtin_bit_cast(unsigned, f);
    return (short)((u + 0x8000u) >> 16);
}
__device__ __forceinline__ float bits2f(short s) {
    unsigned u = (unsigned)(unsigned short)s << 16;
    return __builtin_bit_cast(float, u);
}
// raw v_exp_f32 (2^x) — bypasses OCML denorm fixup (flush-to-zero is fine here)
__device__ __forceinline__ float fexp2(float x) {
    float r; asm("v_exp_f32 %0, %1" : "=v"(r) : "v"(x)); return r;
}

// async global->LDS, 16 B per lane. lds = WAVE-UNIFORM base (HW adds lane*16).
__device__ __forceinline__ void async16(void* lds, const void* g) {
    __builtin_amdgcn_global_load_lds(
        (const __attribute__((address_space(1))) unsigned int*)g,
        (__attribute__((address_space(3))) unsigned int*)lds, 16, 0, 0);
}

// raw waits/barrier (no compiler-forced vmcnt(0) drain — m201 template)
#define S_VMCNT(n) asm volatile("s_waitcnt vmcnt(" #n ")" ::: "memory")
#define S_LGKM0()  asm volatile("s_waitcnt lgkmcnt(0)" ::: "memory")
#define S_BAR()    __builtin_amdgcn_s_barrier()

// DPP cross-lane (16-lane group) reductions — VALU-latency, no LDS pipe.
template <int CTRL>
__device__ __forceinline__ float dppmov(float x) {
    return __builtin_bit_cast(float,
        __builtin_amdgcn_update_dpp(0, __builtin_bit_cast(int, x), CTRL, 0xf, 0xf, true));
}
__device__ __forceinline__ float red16max(float x) {
    x = fmaxf(x, dppmov<0xB1>(x));
    x = fmaxf(x, dppmov<0x4E>(x));
    x = fmaxf(x, dppmov<0x141>(x));
    x = fmaxf(x, dppmov<0x140>(x));
    return x;
}
__device__ __forceinline__ float red16sum(float x) {
    x += dppmov<0xB1>(x);
    x += dppmov<0x4E>(x);
    x += dppmov<0x141>(x);
    x += dppmov<0x140>(x);
    return x;
}

// ---------------------------------------------------------------------------
// Fused prep: weight transposes (fp32->bf16) + x fp32->bf16 convert.
// ---------------------------------------------------------------------------
__global__ __launch_bounds__(256) void prep_kernel(
    const float* __restrict__ wq, const float* __restrict__ wo,
    const float* __restrict__ x,
    __hip_bfloat16* __restrict__ wqT, __hip_bfloat16* __restrict__ woT,
    __hip_bfloat16* __restrict__ xb) {
    const int t = threadIdx.x;
    const int bx = blockIdx.x;
    if (bx >= 128) {
        const size_t id = (size_t)(bx - 128) * 32 + blockIdx.y;
        const size_t i  = id * 2048 + t * 8;
        float f[8]; __builtin_memcpy(f, x + i, 32);
        short8 v;
#pragma unroll
        for (int j = 0; j < 8; ++j) v[j] = bf16bits(f[j]);
        st8(xb + i, v);
        return;
    }
    __shared__ __hip_bfloat16 tile[32][33];
    const int tx = t % 32, ty = t / 32;
    const int r0 = blockIdx.y * 32;
    const float* src; __hip_bfloat16* dst; int ss, ds, c0;
    if (bx < 96) { src = wq; dst = wqT; ss = 3 * DM; ds = DM; c0 = bx * 32; }
    else         { src = wo; dst = woT; ss = DM;     ds = DM; c0 = (bx - 96) * 32; }
#pragma unroll
    for (int i = 0; i < 4; ++i)
        tile[ty + i * 8][tx] = __float2bfloat16(src[(size_t)(r0 + ty + i * 8) * ss + c0 + tx]);
    __syncthreads();
#pragma unroll
    for (int i = 0; i < 4; ++i)
        dst[(size_t)(c0 + ty + i * 8) * ds + r0 + tx] = tile[tx][ty + i * 8];
}

// ---------------------------------------------------------------------------
// GEMM1: 128x64 tiles, BK=64 as two BK=32 planes. 768 blocks = 3/CU.
// V-column blocks (col0>=2048) write their tile transposed to vT.
// ---------------------------------------------------------------------------
__global__ __launch_bounds__(256) void gemm_qkv(
    const __hip_bfloat16* __restrict__ A,
    const __hip_bfloat16* __restrict__ BT,
    __hip_bfloat16* __restrict__ C,
    __hip_bfloat16* __restrict__ vTg,
    int M, int N, int K) {
    __shared__ short As[2 * 128 * 32];
    __shared__ short Bs[2 * 64 * 32];
    __shared__ short Tv[64 * 132];

    const int t = threadIdx.x;
    const int w = t >> 6, lane = t & 63;
    const int l15 = lane & 15, quad = lane >> 4;
    const int row0 = blockIdx.y * 128;
    const int col0 = blockIdx.x * 64;
    const int wm = w >> 1, wn = w & 1;

    float4v acc[4][2];
#pragma unroll
    for (int i = 0; i < 4; ++i)
#pragma unroll
        for (int j = 0; j < 2; ++j) acc[i][j] = (float4v){0.f, 0.f, 0.f, 0.f};

    const int mloc0 = lane >> 2;
    const int u     = lane & 3;

    for (int k0 = 0; k0 < K; k0 += 64) {
#pragma unroll
        for (int kc = 0; kc < 2; ++kc) {
#pragma unroll
            for (int i = 0; i < 2; ++i) {
                const int c = 2 * w + i;
                async16(&As[kc * 4096 + c * 512],
                        A + (size_t)(row0 + c * 16 + mloc0) * K + k0 + kc * 32 + u * 8);
            }
            async16(&Bs[kc * 2048 + w * 512],
                    BT + (size_t)(col0 + w * 16 + mloc0) * K + k0 + kc * 32 + u * 8);
        }
        __syncthreads();

#pragma unroll
        for (int kc = 0; kc < 2; ++kc) {
            short8 af[4], bf[2];
#pragma unroll
            for (int mt = 0; mt < 4; ++mt)
                af[mt] = ld8(&As[kc * 4096 + (wm * 64 + mt * 16 + l15) * 32 + quad * 8]);
#pragma unroll
            for (int nt = 0; nt < 2; ++nt)
                bf[nt] = ld8(&Bs[kc * 2048 + (wn * 32 + nt * 16 + l15) * 32 + quad * 8]);
#pragma unroll
            for (int mt = 0; mt < 4; ++mt)
#pragma unroll
                for (int nt = 0; nt < 2; ++nt)
                    acc[mt][nt] = __builtin_amdgcn_mfma_f32_16x16x32_bf16(
                        af[mt], bf[nt], acc[mt][nt], 0, 0, 0);
        }
        __syncthreads();
    }

    if (col0 < 2 * DM) {
#pragma unroll
        for (int mt = 0; mt < 4; ++mt)
#pragma unroll
            for (int nt = 0; nt < 2; ++nt)
#pragma unroll
                for (int r = 0; r < 4; ++r) {
                    const int row = row0 + wm * 64 + mt * 16 + quad * 4 + r;
                    const int col = col0 + wn * 32 + nt * 16 + l15;
                    C[(size_t)row * N + col] = __float2bfloat16(acc[mt][nt][r]);
                }
    } else {
#pragma unroll
        for (int mt = 0; mt < 4; ++mt)
#pragma unroll
            for (int nt = 0; nt < 2; ++nt)
#pragma unroll
                for (int r = 0; r < 4; ++r)
                    Tv[(wn * 32 + nt * 16 + l15) * 132 + wm * 64 + mt * 16 + quad * 4 + r] =
                        bf16bits(acc[mt][nt][r]);
        __syncthreads();
#pragma unroll
        for (int p = 0; p < 4; ++p) {
            const int idx = p * 256 + t;
            const int dl = idx >> 4, uu = idx & 15;
            st8(&vTg[((size_t)(col0 - 2 * DM) + dl) * SEQ + row0 + uu * 8],
                ld8(&Tv[dl * 132 + uu * 8]));
        }
    }
}

// ---------------------------------------------------------------------------
// GEMM3: 64x64 tiles, BK=64. fp32 out. 512 blocks = 2/CU.
// ---------------------------------------------------------------------------
__global__ __launch_bounds__(256) void gemm_out(
    const __hip_bfloat16* __restrict__ A,
    const __hip_bfloat16* __restrict__ BT,
    float* __restrict__ C,
    int M, int N, int K) {
    __shared__ short As[2 * 64 * 32];
    __shared__ short Bs[2 * 64 * 32];

    const int t = threadIdx.x;
    const int w = t >> 6, lane = t & 63;
    const int l15 = lane & 15, quad = lane >> 4;
    const int row0 = blockIdx.y * 64;
    const int col0 = blockIdx.x * 64;
    const int wm = w >> 1, wn = w & 1;

    float4v acc[2][2];
#pragma unroll
    for (int i = 0; i < 2; ++i)
#pragma unroll
        for (int j = 0; j < 2; ++j) acc[i][j] = (float4v){0.f, 0.f, 0.f, 0.f};

    const int mloc0 = lane >> 2;
    const int u     = lane & 3;

    for (int k0 = 0; k0 < K; k0 += 64) {
#pragma unroll
        for (int kc = 0; kc < 2; ++kc) {
            async16(&As[kc * 2048 + w * 512],
                    A + (size_t)(row0 + w * 16 + mloc0) * K + k0 + kc * 32 + u * 8);
            async16(&Bs[kc * 2048 + w * 512],
                    BT + (size_t)(col0 + w * 16 + mloc0) * K + k0 + kc * 32 + u * 8);
        }
        __syncthreads();

#pragma unroll
        for (int kc = 0; kc < 2; ++kc) {
            short8 af[2], bf[2];
#pragma unroll
            for (int mt = 0; mt < 2; ++mt)
                af[mt] = ld8(&As[kc * 2048 + (wm * 32 + mt * 16 + l15) * 32 + quad * 8]);
#pragma unroll
            for (int nt = 0; nt < 2; ++nt)
                bf[nt] = ld8(&Bs[kc * 2048 + (wn * 32 + nt * 16 + l15) * 32 + quad * 8]);
#pragma unroll
            for (int mt = 0; mt < 2; ++mt)
#pragma unroll
                for (int nt = 0; nt < 2; ++nt)
                    acc[mt][nt] = __builtin_amdgcn_mfma_f32_16x16x32_bf16(
                        af[mt], bf[nt], acc[mt][nt], 0, 0, 0);
        }
        __syncthreads();
    }

#pragma unroll
    for (int mt = 0; mt < 2; ++mt)
#pragma unroll
        for (int nt = 0; nt < 2; ++nt)
#pragma unroll
            for (int r = 0; r < 4; ++r) {
                const int row = row0 + wm * 32 + mt * 16 + quad * 4 + r;
                const int col = col0 + wn * 32 + nt * 16 + l15;
                C[(size_t)row * N + col] = acc[mt][nt][r];
            }
}

// ---------------------------------------------------------------------------
// MFMA flash attention v2: TK=64, K AND V double-buffered via global_load_lds
// with counted vmcnt(4) (prefetch spans a full iteration, never drained to 0
// in-loop), raw s_barrier (2/tile), XOR-swizzled linear LDS (pre-swizzled
// global source per both-sides-or-neither rule), separate per-wave P region
// (odd-dword stride 66 shorts -> conflict-free pf reads).
// grid = 512 1D blocks; decode: xcd=id&7, qb=(id>>3)&31, h=(id&7)+8*(id>>8).
// ---------------------------------------------------------------------------
#define TK   64            // keys per tile
#define NT   (SEQ / TK)    // 32 tiles
#define PSTR 66            // P row stride (shorts) = 33 dwords, odd -> no conflicts

__global__ __launch_bounds__(256) void attn_mfma(
    const __hip_bfloat16* __restrict__ qkv,
    const __hip_bfloat16* __restrict__ vT,
    const float* __restrict__ rel_bias,
    __hip_bfloat16* __restrict__ attnb) {
    __shared__ short Kt[2][TK * 64];     // [key][d]  linear 128B rows, swz content (16 KiB)
    __shared__ short Vt[2][DH * TK];     // [d][key]  linear 128B rows, swz content (16 KiB)
    __shared__ short Pl[4][16 * PSTR];   // per-wave P[q][key] (8.25 KiB)
    __shared__ float biasL[MAXD];

    const int t = threadIdx.x;
    const int w = t >> 6, lane = t & 63;
    const int l15 = lane & 15, quad = lane >> 4;

    const int id = blockIdx.x;           // XCD swizzle: id%8 = XCD (round-robin)
    const int qb = (id >> 3) & 31;
    const int h  = (id & 7) + 8 * (id >> 8);
    const int q0 = qb * 64;
    const int qw = q0 + w * 16;

    if (t < MAXD) biasL[t] = rel_bias[t * NH + h] * LOG2E;

    // persistent Q fragments, pre-scaled by 0.125*log2e (exp2 domain)
    short8 qf[2];
#pragma unroll
    for (int c = 0; c < 2; ++c) {
        short8 raw = ld8(qkv + (size_t)(qw + l15) * (3 * DM) + h * DH + c * 32 + quad * 8);
#pragma unroll
        for (int j = 0; j < 8; ++j) qf[c][j] = bf16bits(bits2f(raw[j]) * (0.125f * LOG2E));
    }

    // --- staging source pointers, pre-swizzled for linear LDS dest -----------
    // round r covers LDS bytes o = r*4096 + w*1024 + lane*16 of an 8 KiB tile;
    // row = o>>7 (128 B rows), colb = o&127; source col = colb ^ ((row&7)<<4)
    const char* kp[2]; const char* vp[2];
    {
        const char* kqb = (const char*)qkv + (size_t)(DM + h * DH) * 2;
        const char* vqb = (const char*)vT  + (size_t)(h * DH) * SEQ * 2;
#pragma unroll
        for (int r = 0; r < 2; ++r) {
            const int o    = r * 4096 + w * 1024 + lane * 16;
            const int row  = o >> 7, colb = o & 127;
            const int sw   = (row & 7) << 4;
            kp[r] = kqb + (size_t)row * (3 * DM * 2) + (colb ^ sw);   // K row = key
            vp[r] = vqb + (size_t)row * (SEQ * 2)    + (colb ^ sw);   // V row = d
        }
    }
    const int ldso = w * 512;  // per-wave LDS base (shorts); HW adds lane*16 B

    // prologue: stage tile 0 (K and V)
#pragma unroll
    for (int r = 0; r < 2; ++r) async16(&Kt[0][r * 2048 + ldso], kp[r]);
#pragma unroll
    for (int r = 0; r < 2; ++r) async16(&Vt[0][r * 2048 + ldso], vp[r]);
#pragma unroll
    for (int r = 0; r < 2; ++r) { kp[r] += (size_t)TK * 3 * DM * 2; vp[r] += TK * 2; }

    float4v o_acc[4];
#pragma unroll
    for (int nt = 0; nt < 4; ++nt) o_acc[nt] = (float4v){0.f, 0.f, 0.f, 0.f};
    float m_i[4], l_i[4];
#pragma unroll
    for (int r = 0; r < 4; ++r) { m_i[r] = -1e30f; l_i[r] = 0.f; }

    const int swz = (l15 & 7) << 4;                              // byte XOR for reads
    const int ka0 = (l15 * 128 + ((quad * 16) ^ swz)) >> 1;      // shorts, c=0
    const int ka1 = (l15 * 128 + (((64) + quad * 16) ^ swz)) >> 1;

    S_LGKM0();   // bias ds_writes retired before first barrier publishes them

    for (int kb = 0; kb < NT; ++kb) {
        const int k0  = kb * TK;
        const int cur = kb & 1, nxt = cur ^ 1;

        // A: prefetch tile kb+1 (last iter overshoots into valid ws; never read)
#pragma unroll
        for (int r = 0; r < 2; ++r) async16(&Kt[nxt][r * 2048 + ldso], kp[r]);
#pragma unroll
        for (int r = 0; r < 2; ++r) async16(&Vt[nxt][r * 2048 + ldso], vp[r]);
#pragma unroll
        for (int r = 0; r < 2; ++r) { kp[r] += (size_t)TK * 3 * DM * 2; vp[r] += TK * 2; }

        // A2: tile kb resident (4 oldest done; 4 newest = next tile stay in flight)
        S_VMCNT(4);
        S_BAR();

        // B: S = Q K^T (exp2 domain)
        float4v s_acc[4];
#pragma unroll
        for (int kt = 0; kt < 4; ++kt) s_acc[kt] = (float4v){0.f, 0.f, 0.f, 0.f};
        const short* Kc = Kt[cur];
#pragma unroll
        for (int kt = 0; kt < 4; ++kt) {
            short8 kf = ld8(Kc + kt * 1024 + ka0);
            s_acc[kt] = __builtin_amdgcn_mfma_f32_16x16x32_bf16(qf[0], kf, s_acc[kt], 0, 0, 0);
        }
#pragma unroll
        for (int kt = 0; kt < 4; ++kt) {
            short8 kf = ld8(Kc + kt * 1024 + ka1);
            s_acc[kt] = __builtin_amdgcn_mfma_f32_16x16x32_bf16(qf[1], kf, s_acc[kt], 0, 0, 0);
        }

        // bias (wave-uniform fast path at max distance)
        float sv[4][4];
        const int dlo = k0 - (qw + 15);
        const int dhi = qw - (k0 + TK - 1);
        if (dlo >= MAXD - 1 || dhi >= MAXD - 1) {
            const float bu = biasL[MAXD - 1];
#pragma unroll
            for (int kt = 0; kt < 4; ++kt)
#pragma unroll
                for (int r = 0; r < 4; ++r) sv[kt][r] = s_acc[kt][r] + bu;
        } else {
#pragma unroll
            for (int kt = 0; kt < 4; ++kt)
#pragma unroll
                for (int r = 0; r < 4; ++r) {
                    const int kg = k0 + kt * 16 + l15;
                    const int qg = qw + quad * 4 + r;
                    int rel = kg - qg; if (rel < 0) rel = -rel;
                    if (rel > MAXD - 1) rel = MAXD - 1;
                    sv[kt][r] = s_acc[kt][r] + biasL[rel];
                }
        }

        // online softmax (exp2 domain, raw v_exp, DPP reductions)
        float rowm[4];
#pragma unroll
        for (int r = 0; r < 4; ++r) {
            float m = sv[0][r];
#pragma unroll
            for (int kt = 1; kt < 4; ++kt) m = fmaxf(m, sv[kt][r]);
            rowm[r] = red16max(m);
        }

        float al[4], rs[4];
#pragma unroll
        for (int r = 0; r < 4; ++r) {
            const float mn = fmaxf(m_i[r], rowm[r]);
            al[r] = fexp2(m_i[r] - mn);
            m_i[r] = mn;
            rs[r] = 0.f;
        }
#pragma unroll
        for (int kt = 0; kt < 4; ++kt)
#pragma unroll
            for (int r = 0; r < 4; ++r) {
                const float p = fexp2(sv[kt][r] - m_i[r]);
                sv[kt][r] = p;
                rs[r] += p;
            }
#pragma unroll
        for (int r = 0; r < 4; ++r) {
            rs[r] = red16sum(rs[r]);
            l_i[r] = l_i[r] * al[r] + rs[r];
        }
#pragma unroll
        for (int nt = 0; nt < 4; ++nt)
#pragma unroll
            for (int r = 0; r < 4; ++r) o_acc[nt][r] *= al[r];

        // P -> own wave's LDS region (same-wave RAW handled by compiler lgkmcnt)
#pragma unroll
        for (int kt = 0; kt < 4; ++kt)
#pragma unroll
            for (int r = 0; r < 4; ++r)
                Pl[w][(quad * 4 + r) * PSTR + kt * 16 + l15] = bf16fast(sv[kt][r]);

        // F: O += P V
        const short* Vc = Vt[cur];
#pragma unroll
        for (int kc = 0; kc < 2; ++kc) {
            short8 pf = ld8(&Pl[w][l15 * PSTR + kc * 32 + quad * 8]);
            const int va = ((kc * 64 + quad * 16) ^ swz) >> 1;
#pragma unroll
            for (int nt = 0; nt < 4; ++nt) {
                short8 vf = ld8(Vc + (nt * 16 + l15) * 64 + va);
                o_acc[nt] = __builtin_amdgcn_mfma_f32_16x16x32_bf16(pf, vf, o_acc[nt], 0, 0, 0);
            }
        }

        // G: all waves done reading Kt[cur]/Vt[cur] -> safe overwrite next iter
        S_BAR();
    }

    // drain prefetch DMA before LDS dealloc at wave exit
    S_VMCNT(0);

    // normalize + store
#pragma unroll
    for (int nt = 0; nt < 4; ++nt)
#pragma unroll
        for (int r = 0; r < 4; ++r) {
            const int row = qw + quad * 4 + r;
            const int col = h * DH + nt * 16 + l15;
            attnb[(size_t)row * DM + col] = __float2bfloat16(o_acc[nt][r] / l_i[r]);
        }
}

extern "C" void kernel_launch(void* const* d_in, const int* in_sizes, int n_in,
                              void* d_out, int out_size, void* d_ws, size_t ws_size,
                              hipStream_t stream) {
    const float* x        = (const float*)d_in[0];
    const float* w_qkv    = (const float*)d_in[1];
    const float* w_out    = (const float*)d_in[2];
    const float* rel_bias = (const float*)d_in[3];
    float* out = (float*)d_out;

    // ws layout (16-B aligned), 32 MiB total
    char* p = (char*)d_ws;
    __hip_bfloat16* xb    = (__hip_bfloat16*)p;  p += (size_t)SEQ * DM * 2;      // 4 MiB
    __hip_bfloat16* wqT   = (__hip_bfloat16*)p;  p += (size_t)3 * DM * DM * 2;   // 6 MiB
    __hip_bfloat16* woT   = (__hip_bfloat16*)p;  p += (size_t)DM * DM * 2;       // 2 MiB
    __hip_bfloat16* qkvb  = (__hip_bfloat16*)p;  p += (size_t)SEQ * 3 * DM * 2;  // 12 MiB
    __hip_bfloat16* vT    = (__hip_bfloat16*)p;  p += (size_t)DM * SEQ * 2;      // 4 MiB
    __hip_bfloat16* attnb = (__hip_bfloat16*)p;                                  // 4 MiB

    prep_kernel<<<dim3(160, 32), 256, 0, stream>>>(w_qkv, w_out, x, wqT, woT, xb);

    // 1) qkv = x @ w_qkv; V-columns written transposed to vT in-epilogue
    gemm_qkv<<<dim3(3 * DM / 64, SEQ / 128), 256, 0, stream>>>(
        xb, wqT, qkvb, vT, SEQ, 3 * DM, DM);

    // 2) attention (single kernel, XCD-swizzled 1D grid, async-pipelined K/V)
    attn_mfma<<<512, 256, 0, stream>>>(qkvb, vT, rel_bias, attnb);

    // 3) out = attn @ w_out
    gemm_out<<<dim3(DM / 64, SEQ / 64), 256, 0, stream>>>(
        attnb, woT, out, SEQ, DM, DM);
}

// Round 2
// 158.764 us; speedup vs baseline: 1.0410x; 1.0410x over previous
//
#include <hip/hip_runtime.h>
#include <hip/hip_bf16.h>

#define SEQ   2048
#define DM    1024
#define NH    16
#define DH    64
#define MAXD  128

#define LOG2E 1.44269504f

typedef __attribute__((ext_vector_type(8))) short  short8;   // 8 bf16 = 4 VGPRs
typedef __attribute__((ext_vector_type(4))) float  float4v;  // MFMA 16x16 accumulator

__device__ __forceinline__ short8 ld8(const void* p) {
    short8 v; __builtin_memcpy(&v, p, 16); return v;
}
__device__ __forceinline__ void st8(void* p, short8 v) {
    __builtin_memcpy(p, &v, 16);
}
__device__ __forceinline__ short bf16bits(float f) {
    __hip_bfloat16 b = __float2bfloat16(f);
    short s; __builtin_memcpy(&s, &b, 2); return s;
}
// fast bf16 pack: round-half-up (2 VALU ops). Used on P in [0,1].
__device__ __forceinline__ short bf16fast(float f) {
    unsigned u = __builtin_bit_cast(unsigned, f);
    return (short)((u + 0x8000u) >> 16);
}
__device__ __forceinline__ float bits2f(short s) {
    unsigned u = (unsigned)(unsigned short)s << 16;
    return __builtin_bit_cast(float, u);
}
// raw v_exp_f32 (2^x) — bypasses OCML denorm fixup (flush-to-zero is fine here)
__device__ __forceinline__ float fexp2(float x) {
    float r; asm("v_exp_f32 %0, %1" : "=v"(r) : "v"(x)); return r;
}

// async global->LDS, 16 B per lane. lds = WAVE-UNIFORM base (HW adds lane*16).
__device__ __forceinline__ void async16(void* lds, const void* g) {
    __builtin_amdgcn_global_load_lds(
        (const __attribute__((address_space(1))) unsigned int*)g,
        (__attribute__((address_space(3))) unsigned int*)lds, 16, 0, 0);
}

// raw waits/barrier — avoid the compiler's full vmcnt(0)+lgkmcnt(0) drain at
// __syncthreads(); publish LDS writes with lgkmcnt(0) only, keep global
// prefetch loads in flight across barriers (T14 async-STAGE split).
#define S_LGKM0()  asm volatile("s_waitcnt lgkmcnt(0)" ::: "memory")
#define S_BAR()    __builtin_amdgcn_s_barrier()

// DPP cross-lane (16-lane group) reductions — VALU-latency, no LDS pipe.
template <int CTRL>
__device__ __forceinline__ float dppmov(float x) {
    return __builtin_bit_cast(float,
        __builtin_amdgcn_update_dpp(0, __builtin_bit_cast(int, x), CTRL, 0xf, 0xf, true));
}
__device__ __forceinline__ float red16max(float x) {
    x = fmaxf(x, dppmov<0xB1>(x));
    x = fmaxf(x, dppmov<0x4E>(x));
    x = fmaxf(x, dppmov<0x141>(x));
    x = fmaxf(x, dppmov<0x140>(x));
    return x;
}
__device__ __forceinline__ float red16sum(float x) {
    x += dppmov<0xB1>(x);
    x += dppmov<0x4E>(x);
    x += dppmov<0x141>(x);
    x += dppmov<0x140>(x);
    return x;
}

// ---------------------------------------------------------------------------
// Fused prep: weight transposes (fp32->bf16) + x fp32->bf16 convert.
// ---------------------------------------------------------------------------
__global__ __launch_bounds__(256) void prep_kernel(
    const float* __restrict__ wq, const float* __restrict__ wo,
    const float* __restrict__ x,
    __hip_bfloat16* __restrict__ wqT, __hip_bfloat16* __restrict__ woT,
    __hip_bfloat16* __restrict__ xb) {
    const int t = threadIdx.x;
    const int bx = blockIdx.x;
    if (bx >= 128) {
        const size_t id = (size_t)(bx - 128) * 32 + blockIdx.y;
        const size_t i  = id * 2048 + t * 8;
        float f[8]; __builtin_memcpy(f, x + i, 32);
        short8 v;
#pragma unroll
        for (int j = 0; j < 8; ++j) v[j] = bf16bits(f[j]);
        st8(xb + i, v);
        return;
    }
    __shared__ __hip_bfloat16 tile[32][33];
    const int tx = t % 32, ty = t / 32;
    const int r0 = blockIdx.y * 32;
    const float* src; __hip_bfloat16* dst; int ss, ds, c0;
    if (bx < 96) { src = wq; dst = wqT; ss = 3 * DM; ds = DM; c0 = bx * 32; }
    else         { src = wo; dst = woT; ss = DM;     ds = DM; c0 = (bx - 96) * 32; }
#pragma unroll
    for (int i = 0; i < 4; ++i)
        tile[ty + i * 8][tx] = __float2bfloat16(src[(size_t)(r0 + ty + i * 8) * ss + c0 + tx]);
    __syncthreads();
#pragma unroll
    for (int i = 0; i < 4; ++i)
        dst[(size_t)(c0 + ty + i * 8) * ds + r0 + tx] = tile[tx][ty + i * 8];
}

// ---------------------------------------------------------------------------
// GEMM1: 128x64 tiles, BK=64 as two BK=32 planes. 768 blocks = 3/CU.
// V-column blocks (col0>=2048) write their tile transposed to vT.
// ---------------------------------------------------------------------------
__global__ __launch_bounds__(256) void gemm_qkv(
    const __hip_bfloat16* __restrict__ A,
    const __hip_bfloat16* __restrict__ BT,
    __hip_bfloat16* __restrict__ C,
    __hip_bfloat16* __restrict__ vTg,
    int M, int N, int K) {
    __shared__ short As[2 * 128 * 32];
    __shared__ short Bs[2 * 64 * 32];
    __shared__ short Tv[64 * 132];

    const int t = threadIdx.x;
    const int w = t >> 6, lane = t & 63;
    const int l15 = lane & 15, quad = lane >> 4;
    const int row0 = blockIdx.y * 128;
    const int col0 = blockIdx.x * 64;
    const int wm = w >> 1, wn = w & 1;

    float4v acc[4][2];
#pragma unroll
    for (int i = 0; i < 4; ++i)
#pragma unroll
        for (int j = 0; j < 2; ++j) acc[i][j] = (float4v){0.f, 0.f, 0.f, 0.f};

    const int mloc0 = lane >> 2;
    const int u     = lane & 3;

    for (int k0 = 0; k0 < K; k0 += 64) {
#pragma unroll
        for (int kc = 0; kc < 2; ++kc) {
#pragma unroll
            for (int i = 0; i < 2; ++i) {
                const int c = 2 * w + i;
                async16(&As[kc * 4096 + c * 512],
                        A + (size_t)(row0 + c * 16 + mloc0) * K + k0 + kc * 32 + u * 8);
            }
            async16(&Bs[kc * 2048 + w * 512],
                    BT + (size_t)(col0 + w * 16 + mloc0) * K + k0 + kc * 32 + u * 8);
        }
        __syncthreads();

#pragma unroll
        for (int kc = 0; kc < 2; ++kc) {
            short8 af[4], bf[2];
#pragma unroll
            for (int mt = 0; mt < 4; ++mt)
                af[mt] = ld8(&As[kc * 4096 + (wm * 64 + mt * 16 + l15) * 32 + quad * 8]);
#pragma unroll
            for (int nt = 0; nt < 2; ++nt)
                bf[nt] = ld8(&Bs[kc * 2048 + (wn * 32 + nt * 16 + l15) * 32 + quad * 8]);
#pragma unroll
            for (int mt = 0; mt < 4; ++mt)
#pragma unroll
                for (int nt = 0; nt < 2; ++nt)
                    acc[mt][nt] = __builtin_amdgcn_mfma_f32_16x16x32_bf16(
                        af[mt], bf[nt], acc[mt][nt], 0, 0, 0);
        }
        __syncthreads();
    }

    if (col0 < 2 * DM) {
#pragma unroll
        for (int mt = 0; mt < 4; ++mt)
#pragma unroll
            for (int nt = 0; nt < 2; ++nt)
#pragma unroll
                for (int r = 0; r < 4; ++r) {
                    const int row = row0 + wm * 64 + mt * 16 + quad * 4 + r;
                    const int col = col0 + wn * 32 + nt * 16 + l15;
                    C[(size_t)row * N + col] = __float2bfloat16(acc[mt][nt][r]);
                }
    } else {
#pragma unroll
        for (int mt = 0; mt < 4; ++mt)
#pragma unroll
            for (int nt = 0; nt < 2; ++nt)
#pragma unroll
                for (int r = 0; r < 4; ++r)
                    Tv[(wn * 32 + nt * 16 + l15) * 132 + wm * 64 + mt * 16 + quad * 4 + r] =
                        bf16bits(acc[mt][nt][r]);
        __syncthreads();
#pragma unroll
        for (int p = 0; p < 4; ++p) {
            const int idx = p * 256 + t;
            const int dl = idx >> 4, uu = idx & 15;
            st8(&vTg[((size_t)(col0 - 2 * DM) + dl) * SEQ + row0 + uu * 8],
                ld8(&Tv[dl * 132 + uu * 8]));
        }
    }
}

// ---------------------------------------------------------------------------
// GEMM3: 64x64 tiles, BK=64. fp32 out. 512 blocks = 2/CU.
// ---------------------------------------------------------------------------
__global__ __launch_bounds__(256) void gemm_out(
    const __hip_bfloat16* __restrict__ A,
    const __hip_bfloat16* __restrict__ BT,
    float* __restrict__ C,
    int M, int N, int K) {
    __shared__ short As[2 * 64 * 32];
    __shared__ short Bs[2 * 64 * 32];

    const int t = threadIdx.x;
    const int w = t >> 6, lane = t & 63;
    const int l15 = lane & 15, quad = lane >> 4;
    const int row0 = blockIdx.y * 64;
    const int col0 = blockIdx.x * 64;
    const int wm = w >> 1, wn = w & 1;

    float4v acc[2][2];
#pragma unroll
    for (int i = 0; i < 2; ++i)
#pragma unroll
        for (int j = 0; j < 2; ++j) acc[i][j] = (float4v){0.f, 0.f, 0.f, 0.f};

    const int mloc0 = lane >> 2;
    const int u     = lane & 3;

    for (int k0 = 0; k0 < K; k0 += 64) {
#pragma unroll
        for (int kc = 0; kc < 2; ++kc) {
            async16(&As[kc * 2048 + w * 512],
                    A + (size_t)(row0 + w * 16 + mloc0) * K + k0 + kc * 32 + u * 8);
            async16(&Bs[kc * 2048 + w * 512],
                    BT + (size_t)(col0 + w * 16 + mloc0) * K + k0 + kc * 32 + u * 8);
        }
        __syncthreads();

#pragma unroll
        for (int kc = 0; kc < 2; ++kc) {
            short8 af[2], bf[2];
#pragma unroll
            for (int mt = 0; mt < 2; ++mt)
                af[mt] = ld8(&As[kc * 2048 + (wm * 32 + mt * 16 + l15) * 32 + quad * 8]);
#pragma unroll
            for (int nt = 0; nt < 2; ++nt)
                bf[nt] = ld8(&Bs[kc * 2048 + (wn * 32 + nt * 16 + l15) * 32 + quad * 8]);
#pragma unroll
            for (int mt = 0; mt < 2; ++mt)
#pragma unroll
                for (int nt = 0; nt < 2; ++nt)
                    acc[mt][nt] = __builtin_amdgcn_mfma_f32_16x16x32_bf16(
                        af[mt], bf[nt], acc[mt][nt], 0, 0, 0);
        }
        __syncthreads();
    }

#pragma unroll
    for (int mt = 0; mt < 2; ++mt)
#pragma unroll
        for (int nt = 0; nt < 2; ++nt)
#pragma unroll
            for (int r = 0; r < 4; ++r) {
                const int row = row0 + wm * 32 + mt * 16 + quad * 4 + r;
                const int col = col0 + wn * 32 + nt * 16 + l15;
                C[(size_t)row * N + col] = acc[mt][nt][r];
            }
}

// ---------------------------------------------------------------------------
// MFMA flash attention v3: round-0 structure (TK=128, padded strides KS=68 /
// VS=132 — measured 3x fewer bank conflicts than 128B-row XOR layouts) plus
// T14 async-STAGE split: global loads for tile kb+1 issued right after the
// publish barrier, written to LDS at the top of iteration kb+1. Raw s_barrier
// with targeted lgkmcnt(0) only — no compiler vmcnt(0) drain, so the 8
// prefetch loads stay in flight under QK+softmax+PV. Dedicated P region
// (no Kt aliasing) drops the mid-tile barrier: 2 barriers/tile.
// grid = 512 1D blocks; decode: xcd=id&7, qb=(id>>3)&31, h=(id&7)+8*(id>>8).
// ---------------------------------------------------------------------------
#define TK    128            // keys per tile
#define NTILE (SEQ / TK)     // 16 tiles
#define KS    68             // Kt row stride (shorts), 34 dwords (odd-ish mod 32)
#define VS    132            // Vt / Pl row stride (shorts), 66 dwords

__global__ __launch_bounds__(256) void attn_mfma(
    const __hip_bfloat16* __restrict__ qkv,
    const __hip_bfloat16* __restrict__ vT,
    const float* __restrict__ rel_bias,
    __hip_bfloat16* __restrict__ attnb) {
    __shared__ short Kt[TK * KS];        // [key][d]            17.0 KiB
    __shared__ short Vt[DH * VS];        // [d][key]            16.5 KiB
    __shared__ short Pl[4][16 * VS];     // per-wave P[q][key]  16.5 KiB
    __shared__ float biasL[MAXD];

    const int t = threadIdx.x;
    const int w = t >> 6, lane = t & 63;
    const int l15 = lane & 15, quad = lane >> 4;

    const int id = blockIdx.x;           // XCD swizzle: id%8 = XCD (round-robin)
    const int qb = (id >> 3) & 31;
    const int h  = (id & 7) + 8 * (id >> 8);
    const int q0 = qb * 64;
    const int qw = q0 + w * 16;

    if (t < MAXD) biasL[t] = rel_bias[t * NH + h] * LOG2E;

    // persistent Q fragments, pre-scaled by 0.125*log2e (exp2 domain)
    short8 qf[2];
#pragma unroll
    for (int c = 0; c < 2; ++c) {
        short8 raw = ld8(qkv + (size_t)(qw + l15) * (3 * DM) + h * DH + c * 32 + quad * 8);
#pragma unroll
        for (int j = 0; j < 8; ++j) qf[c][j] = bf16bits(bits2f(raw[j]) * (0.125f * LOG2E));
    }

    float4v o_acc[4];
#pragma unroll
    for (int nt = 0; nt < 4; ++nt) o_acc[nt] = (float4v){0.f, 0.f, 0.f, 0.f};
    float m_i[4], l_i[4];
#pragma unroll
    for (int r = 0; r < 4; ++r) { m_i[r] = -1e30f; l_i[r] = 0.f; }

    // prologue: prefetch tile 0 into registers (8 x 16B per thread)
    short8 pk[4], pv[4];
#pragma unroll
    for (int p = 0; p < 4; ++p) {
        const int idx = p * 256 + t;
        pk[p] = ld8(qkv + (size_t)(idx >> 3) * (3 * DM) + DM + h * DH + (idx & 7) * 8);
    }
#pragma unroll
    for (int p = 0; p < 4; ++p) {
        const int idx = p * 256 + t;
        pv[p] = ld8(vT + (size_t)(h * DH + (idx >> 4)) * SEQ + (idx & 15) * 8);
    }

    for (int kb = 0; kb < NTILE; ++kb) {
        const int k0 = kb * TK;

        // A: write staged registers -> LDS (padded layout), publish
#pragma unroll
        for (int p = 0; p < 4; ++p) {
            const int idx = p * 256 + t;
            st8(&Kt[(idx >> 3) * KS + (idx & 7) * 8], pk[p]);
        }
#pragma unroll
        for (int p = 0; p < 4; ++p) {
            const int idx = p * 256 + t;
            st8(&Vt[(idx >> 4) * VS + (idx & 15) * 8], pv[p]);
        }
        S_LGKM0();   // ds_writes (and biasL on iter 0) retired
        S_BAR();     // tile kb visible to all waves

        // B: issue tile kb+1 global loads NOW — retire under compute below
        if (kb + 1 < NTILE) {
            const int kn = k0 + TK;
#pragma unroll
            for (int p = 0; p < 4; ++p) {
                const int idx = p * 256 + t;
                pk[p] = ld8(qkv + (size_t)(kn + (idx >> 3)) * (3 * DM) + DM + h * DH + (idx & 7) * 8);
            }
#pragma unroll
            for (int p = 0; p < 4; ++p) {
                const int idx = p * 256 + t;
                pv[p] = ld8(vT + (size_t)(h * DH + (idx >> 4)) * SEQ + kn + (idx & 15) * 8);
            }
        }

        // C: S = Q K^T (exp2 domain)
        float4v s_acc[8];
#pragma unroll
        for (int kt = 0; kt < 8; ++kt) s_acc[kt] = (float4v){0.f, 0.f, 0.f, 0.f};
#pragma unroll
        for (int c = 0; c < 2; ++c)
#pragma unroll
            for (int kt = 0; kt < 8; ++kt) {
                short8 kf = ld8(&Kt[(kt * 16 + l15) * KS + (c * 4 + quad) * 8]);
                s_acc[kt] = __builtin_amdgcn_mfma_f32_16x16x32_bf16(qf[c], kf, s_acc[kt], 0, 0, 0);
            }

        // bias (wave-uniform fast path at max distance)
        float sv[8][4];
        const int dlo = k0 - (qw + 15);
        const int dhi = qw - (k0 + TK - 1);
        if (dlo >= MAXD - 1 || dhi >= MAXD - 1) {
            const float bu = biasL[MAXD - 1];
#pragma unroll
            for (int kt = 0; kt < 8; ++kt)
#pragma unroll
                for (int r = 0; r < 4; ++r) sv[kt][r] = s_acc[kt][r] + bu;
        } else {
#pragma unroll
            for (int kt = 0; kt < 8; ++kt)
#pragma unroll
                for (int r = 0; r < 4; ++r) {
                    const int kg = k0 + kt * 16 + l15;
                    const int qg = qw + quad * 4 + r;
                    int rel = kg - qg; if (rel < 0) rel = -rel;
                    if (rel > MAXD - 1) rel = MAXD - 1;
                    sv[kt][r] = s_acc[kt][r] + biasL[rel];
                }
        }

        // online softmax (exp2 domain, raw v_exp, DPP reductions)
        float rowm[4];
#pragma unroll
        for (int r = 0; r < 4; ++r) {
            float m = sv[0][r];
#pragma unroll
            for (int kt = 1; kt < 8; ++kt) m = fmaxf(m, sv[kt][r]);
            rowm[r] = red16max(m);
        }

        float al[4], rs[4];
#pragma unroll
        for (int r = 0; r < 4; ++r) {
            const float mn = fmaxf(m_i[r], rowm[r]);
            al[r] = fexp2(m_i[r] - mn);
            m_i[r] = mn;
            rs[r] = 0.f;
        }
#pragma unroll
        for (int kt = 0; kt < 8; ++kt)
#pragma unroll
            for (int r = 0; r < 4; ++r) {
                const float p = fexp2(sv[kt][r] - m_i[r]);
                sv[kt][r] = p;
                rs[r] += p;
            }
#pragma unroll
        for (int r = 0; r < 4; ++r) {
            rs[r] = red16sum(rs[r]);
            l_i[r] = l_i[r] * al[r] + rs[r];
        }
#pragma unroll
        for (int nt = 0; nt < 4; ++nt)
#pragma unroll
            for (int r = 0; r < 4; ++r) o_acc[nt][r] *= al[r];

        // D: P -> own wave's region (same-wave RAW ordered by LDS FIFO+lgkmcnt)
#pragma unroll
        for (int kt = 0; kt < 8; ++kt)
#pragma unroll
            for (int r = 0; r < 4; ++r)
                Pl[w][(quad * 4 + r) * VS + kt * 16 + l15] = bf16fast(sv[kt][r]);

        // E: O += P V
#pragma unroll
        for (int kc = 0; kc < 4; ++kc) {
            short8 pf = ld8(&Pl[w][l15 * VS + kc * 32 + quad * 8]);
#pragma unroll
            for (int nt = 0; nt < 4; ++nt) {
                short8 vf = ld8(&Vt[(nt * 16 + l15) * VS + kc * 32 + quad * 8]);
                o_acc[nt] = __builtin_amdgcn_mfma_f32_16x16x32_bf16(pf, vf, o_acc[nt], 0, 0, 0);
            }
        }

        // F: all waves' Kt/Vt reads retired (data-dep before arrival) ->
        //    safe to overwrite at next iteration's stage phase
        S_BAR();
    }

    // normalize + store
#pragma unroll
    for (int nt = 0; nt < 4; ++nt)
#pragma unroll
        for (int r = 0; r < 4; ++r) {
            const int row = qw + quad * 4 + r;
            const int col = h * DH + nt * 16 + l15;
            attnb[(size_t)row * DM + col] = __float2bfloat16(o_acc[nt][r] / l_i[r]);
        }
}

extern "C" void kernel_launch(void* const* d_in, const int* in_sizes, int n_in,
                              void* d_out, int out_size, void* d_ws, size_t ws_size,
                              hipStream_t stream) {
    const float* x        = (const float*)d_in[0];
    const float* w_qkv    = (const float*)d_in[1];
    const float* w_out    = (const float*)d_in[2];
    const float* rel_bias = (const float*)d_in[3];
    float* out = (float*)d_out;

    // ws layout (16-B aligned), 32 MiB total
    char* p = (char*)d_ws;
    __hip_bfloat16* xb    = (__hip_bfloat16*)p;  p += (size_t)SEQ * DM * 2;      // 4 MiB
    __hip_bfloat16* wqT   = (__hip_bfloat16*)p;  p += (size_t)3 * DM * DM * 2;   // 6 MiB
    __hip_bfloat16* woT   = (__hip_bfloat16*)p;  p += (size_t)DM * DM * 2;       // 2 MiB
    __hip_bfloat16* qkvb  = (__hip_bfloat16*)p;  p += (size_t)SEQ * 3 * DM * 2;  // 12 MiB
    __hip_bfloat16* vT    = (__hip_bfloat16*)p;  p += (size_t)DM * SEQ * 2;      // 4 MiB
    __hip_bfloat16* attnb = (__hip_bfloat16*)p;                                  // 4 MiB

    prep_kernel<<<dim3(160, 32), 256, 0, stream>>>(w_qkv, w_out, x, wqT, woT, xb);

    // 1) qkv = x @ w_qkv; V-columns written transposed to vT in-epilogue
    gemm_qkv<<<dim3(3 * DM / 64, SEQ / 128), 256, 0, stream>>>(
        xb, wqT, qkvb, vT, SEQ, 3 * DM, DM);

    // 2) attention (single kernel, XCD-swizzled 1D grid, reg-prefetch pipeline)
    attn_mfma<<<512, 256, 0, stream>>>(qkvb, vT, rel_bias, attnb);

    // 3) out = attn @ w_out
    gemm_out<<<dim3(DM / 64, SEQ / 64), 256, 0, stream>>>(
        attnb, woT, out, SEQ, DM, DM);
}